// Round 24
// baseline (209.835 us; speedup 1.0000x reference)
//
#include <hip/hip_runtime.h>
#include <hip/hip_cooperative_groups.h>
#include <math.h>

namespace cg = cooperative_groups;

// Static problem dims
#define B_   2
#define N_   6
#define D_   60
#define FH_  28
#define FW_  60
#define C_   64
#define NX_  200
#define NY_  200
#define HW_  (FH_*FW_)       // 1680
#define NPIX_ (B_*N_*HW_)    // 20160
#define DSPLIT 15
#define DCHUNK (D_/DSPLIT)   // 4
#define ACC_N4 ((B_*NX_*NY_*C_)/4)   // 1,280,000 float4s
#define NSMBLK ((NPIX_+255)/256)     // 79 softmax blocks
#define NTTILE ((HW_+63)/64)         // 27 transpose tiles per bn
#define NTRB   (B_*N_*NTTILE)        // 324 transpose blocks
#define NROLE  (NSMBLK+NTRB)         // 403
#define NWAVES (B_*N_*FW_*DSPLIT)    // 10800 scatter waves
#define NOUTT  (B_*(NX_*NY_/64))     // 1250 out tiles

// ---------------------------------------------------------------------------
// Shared device routine: the 12 4x4 inverses (OpenBLAS sgesv, VERIFIED R17).
// ---------------------------------------------------------------------------
__device__ void inv12(const float* __restrict__ l2i, float* __restrict__ minv, int m) {
#pragma clang fp contract(off)
    float a[4][4];
    for (int r = 0; r < 4; r++)
        for (int c = 0; c < 4; c++)
            a[r][c] = l2i[m * 16 + r * 4 + c];
    int ipiv[4];
    for (int j = 0; j < 4; j++) {
        int jp = j; float amax = fabsf(a[j][j]);
        for (int i = j + 1; i < 4; i++) {
            float v = fabsf(a[i][j]);
            if (v > amax) { amax = v; jp = i; }
        }
        ipiv[j] = jp;
        if (jp != j)
            for (int c = 0; c < 4; c++) { float t = a[j][c]; a[j][c] = a[jp][c]; a[jp][c] = t; }
        if (a[j][j] != 0.0f) {
            float rcp = 1.0f / a[j][j];
            for (int i = j + 1; i < 4; i++) a[i][j] = a[i][j] * rcp;
        }
        for (int k = j + 1; k < 4; k++) {
            float temp = -a[j][k];
            if (temp != 0.0f)
                for (int i = j + 1; i < 4; i++)
                    a[i][k] = fmaf(a[i][j], temp, a[i][k]);
        }
    }
    float bmat[4][4];
    for (int r = 0; r < 4; r++)
        for (int c = 0; c < 4; c++) bmat[r][c] = (r == c) ? 1.0f : 0.0f;
    for (int j = 0; j < 4; j++) {
        int jp = ipiv[j];
        if (jp != j)
            for (int c = 0; c < 4; c++) { float t = bmat[j][c]; bmat[j][c] = bmat[jp][c]; bmat[jp][c] = t; }
    }
    for (int c = 0; c < 4; c++)
        for (int k = 0; k < 4; k++) {
            float bk = bmat[k][c];
            if (bk != 0.0f)
                for (int i = k + 1; i < 4; i++)
                    bmat[i][c] = fmaf(-bk, a[i][k], bmat[i][c]);
        }
    float dinv[4];
    for (int k = 0; k < 4; k++) dinv[k] = 1.0f / a[k][k];
    for (int c = 0; c < 4; c++)
        for (int k = 3; k >= 0; k--) {
            float bk = bmat[k][c];
            if (bk != 0.0f) {
                bk = bk * dinv[k];
                bmat[k][c] = bk;
                for (int i = 0; i < k; i++)
                    bmat[i][c] = fmaf(-bk, a[i][k], bmat[i][c]);
            }
        }
    for (int r = 0; r < 4; r++)
        for (int c = 0; c < 4; c++)
            minv[m * 16 + r * 4 + c] = bmat[r][c];
}

// Shared device routines for the phases (identical arithmetic to R22).
__device__ void softmax_block(const float* __restrict__ depth, float* __restrict__ wt,
                              int smblk, int tid) {
    int p = smblk * 256 + tid;
    if (p >= NPIX_) return;
    int bn = p / HW_;
    int hw = p - bn * HW_;
    const float* dptr = depth + (size_t)bn * D_ * HW_ + hw;
    float v[D_];
    float mx = -1e30f;
    #pragma unroll
    for (int d = 0; d < D_; d++) { v[d] = dptr[(size_t)d * HW_]; mx = fmaxf(mx, v[d]); }
    float s = 0.f;
    #pragma unroll
    for (int d = 0; d < D_; d++) { v[d] = expf(v[d] - mx); s += v[d]; }
    float is = 1.f / s;
    float* o = wt + (size_t)p * D_;
    #pragma unroll
    for (int d = 0; d < D_; d++) o[d] = v[d] * is;
}

__device__ void tfeat_block(const float* __restrict__ feats, float* __restrict__ ft,
                            float (*tile)[65], int bid, int tid) {
    int bn = bid / NTTILE;
    int p0 = (bid % NTTILE) * 64;
    int tx = tid & 63;
    int ty = tid >> 6;
    const float* src = feats + (size_t)bn * C_ * HW_;
    #pragma unroll
    for (int k = 0; k < 16; k++) {
        int c = ty * 16 + k;
        int p = p0 + tx;
        if (p < HW_) tile[c][tx] = src[(size_t)c * HW_ + p];
    }
    __syncthreads();
    float* dst = ft + (size_t)bn * HW_ * C_;
    #pragma unroll
    for (int k = 0; k < 16; k++) {
        int pl = ty * 16 + k;
        int p = p0 + pl;
        if (p < HW_) dst[(size_t)p * C_ + tx] = tile[tx][pl];
    }
}

__device__ void scatter_wave(const float* __restrict__ frustum,
                             const float* __restrict__ minv,
                             const float* __restrict__ wt,
                             const float* __restrict__ ft,
                             const float* __restrict__ dxp,
                             const float* __restrict__ bxp,
                             float* __restrict__ acc, int wvid, int lane) {
#pragma clang fp contract(off)
    int dq = wvid % DSPLIT;
    int w  = (wvid / DSPLIT) % FW_;
    int bn = wvid / (DSPLIT * FW_);
    int b  = bn / N_;
    int bnbase = bn * HW_;
    int d0 = dq * DCHUNK;

    float ftreg[FH_];
    #pragma unroll
    for (int h = 0; h < FH_; h++)
        ftreg[h] = ft[(size_t)(bnbase + h * FW_ + w) * C_ + lane];

    float u = frustum[w * 3 + 0];
    float v = 0.f;
    float4 w4 = make_float4(0.f, 0.f, 0.f, 0.f);
    if (lane < FH_) {
        v = frustum[((size_t)lane * FW_ + w) * 3 + 1];
        int pix = bnbase + lane * FW_ + w;
        w4 = *reinterpret_cast<const float4*>(&wt[(size_t)pix * D_ + d0]);
    }
    const float* M = minv + (size_t)bn * 16;
    float M0 = M[0], M1 = M[1], M2 = M[2],  M3 = M[3];
    float M4 = M[4], M5 = M[5], M6 = M[6],  M7 = M[7];
    float M8 = M[8], M9 = M[9], M10 = M[10], M11 = M[11];
    float dx0 = dxp[0], dx1 = dxp[1], dx2 = dxp[2];
    float lb0 = bxp[0] - dx0 * 0.5f;
    float lb1 = bxp[1] - dx1 * 0.5f;
    float lb2 = bxp[2] - dx2 * 0.5f;

    #pragma unroll
    for (int k = 0; k < DCHUNK; k++) {
        int d = d0 + k;
        float mywt = (k == 0) ? w4.x : (k == 1) ? w4.y : (k == 2) ? w4.z : w4.w;
        int myenc = -1;
        if (lane < FH_) {
            float dd = (float)(d + 1);
            float dm = fmaxf(dd, 1e-5f);
            float p0 = u * dm;
            float p1 = v * dm;
            float p2 = dd;
            float x0 = M0 * p0, x1 = M1 * p1, x2 = M2 * p2, x3 = M3 * 1.0f;
            float gx = (x0 + x1) + (x2 + x3);
            float y0 = M4 * p0, y1 = M5 * p1, y2 = M6 * p2, y3 = M7 * 1.0f;
            float gy = (y0 + y1) + (y2 + y3);
            float z0 = M8 * p0, z1 = M9 * p1, z2 = M10 * p2, z3 = M11 * 1.0f;
            float gz = (z0 + z1) + (z2 + z3);
            float qx = (gx - lb0) / dx0;
            float qy = (gy - lb1) / dx1;
            float qz = (gz - lb2) / dx2;
            int ix = (int)qx;
            int iy = (int)qy;
            int iz = (int)qz;
            if (ix >= 0 && ix < NX_ && iy >= 0 && iy < NY_ && iz == 0)
                myenc = (((b * NX_) + ix) * NY_ + iy) * C_;
        }
        unsigned long long processed = 0;
        for (int j = 0; j < FH_; ++j) {
            if (processed & (1ull << j)) continue;
            int e = __shfl(myenc, j, 64);
            unsigned long long mm = __ballot(lane < FH_ && myenc == e);
            processed |= mm;
            if (e < 0) continue;
            float s = 0.f;
            #pragma unroll
            for (int h = 0; h < FH_; h++) {
                float wh = __shfl(mywt, h, 64);
                s = fmaf(((mm >> h) & 1ull) ? wh : 0.0f, ftreg[h], s);
            }
            atomicAdd(&acc[(size_t)e + lane], s);
        }
    }
}

__device__ void out_tile(const float* __restrict__ acc, float* __restrict__ out,
                         float (*tile)[65], int vt, int tid) {
    int tx = tid & 63;
    int ty = tid >> 6;
    int b = vt / (NX_ * NY_ / 64);
    int p0 = (vt % (NX_ * NY_ / 64)) * 64;
    const float* src = acc + (size_t)b * (NX_ * NY_) * C_;
    #pragma unroll
    for (int k = 0; k < 16; k++) {
        int pl = ty * 16 + k;
        tile[pl][tx] = src[(size_t)(p0 + pl) * C_ + tx];
    }
    __syncthreads();
    float* dst = out + (size_t)b * C_ * (NX_ * NY_);
    #pragma unroll
    for (int k = 0; k < 16; k++) {
        int c = ty * 16 + k;
        dst[(size_t)c * (NX_ * NY_) + p0 + tx] = tile[tx][c];
    }
}

// ---------------------------------------------------------------------------
// Cooperative fused kernel (grid-size-agnostic; needs gridDim.x >= NROLE+64).
// ---------------------------------------------------------------------------
__global__ void __launch_bounds__(256, 4)
k_fused(const float* __restrict__ l2i, float* __restrict__ minv,
        float4* __restrict__ acc4,
        const float* __restrict__ depth, float* __restrict__ wt,
        const float* __restrict__ feats, float* __restrict__ ft,
        const float* __restrict__ frustum,
        const float* __restrict__ dxp, const float* __restrict__ bxp,
        float* __restrict__ acc, float* __restrict__ out) {
    cg::grid_group grid = cg::this_grid();
    __shared__ float tile[64][65];
    int tid = threadIdx.x;
    int nb = gridDim.x;

    // ===== Phase A =====
    if (blockIdx.x < NSMBLK) {
        softmax_block(depth, wt, blockIdx.x, tid);
    } else if (blockIdx.x < NROLE) {
        tfeat_block(feats, ft, tile, blockIdx.x - NSMBLK, tid);
    } else {
        if (blockIdx.x == NROLE && tid < B_ * N_) inv12(l2i, minv, tid);
        float4 z = make_float4(0.f, 0.f, 0.f, 0.f);
        int base = (blockIdx.x - NROLE) * 256 + tid;
        int stride = (nb - NROLE) * 256;
        for (int i = base; i < ACC_N4; i += stride) acc4[i] = z;
    }

    grid.sync();

    // ===== Phase B: scatter =====
    {
        int lane = tid & 63;
        int gw = blockIdx.x * 4 + (tid >> 6);
        for (int wvid = gw; wvid < NWAVES; wvid += nb * 4)
            scatter_wave(frustum, minv, wt, ft, dxp, bxp, acc, wvid, lane);
    }

    grid.sync();

    // ===== Phase C: acc -> out =====
    for (int vt = blockIdx.x; vt < NOUTT; vt += nb) {
        __syncthreads();
        out_tile(acc, out, tile, vt, tid);
    }
}

// ---------------------------------------------------------------------------
// Fallback path: exact R22 3-kernel pipeline (56.3us, verified).
// ---------------------------------------------------------------------------
__global__ void k_pre(const float* __restrict__ l2i, float* __restrict__ minv_out,
                      float4* __restrict__ acc4,
                      const float* __restrict__ depth, float* __restrict__ wt,
                      const float* __restrict__ feats, float* __restrict__ ft) {
    __shared__ float tile[64][65];
    if (blockIdx.x < 1024) {
        if (blockIdx.x == 0 && threadIdx.x < B_ * N_) inv12(l2i, minv_out, threadIdx.x);
        float4 z = make_float4(0.f, 0.f, 0.f, 0.f);
        int stride = 1024 * 256;
        for (int i = blockIdx.x * 256 + threadIdx.x; i < ACC_N4; i += stride)
            acc4[i] = z;
    } else if (blockIdx.x < 1024 + NSMBLK) {
        softmax_block(depth, wt, blockIdx.x - 1024, threadIdx.x);
    } else {
        tfeat_block(feats, ft, tile, blockIdx.x - 1024 - NSMBLK, threadIdx.x);
    }
}

__global__ void k_scatter4(const float* __restrict__ frustum,
                           const float* __restrict__ minv,
                           const float* __restrict__ wt,
                           const float* __restrict__ ft,
                           const float* __restrict__ dxp,
                           const float* __restrict__ bxp,
                           float* __restrict__ acc) {
    int gtid = blockIdx.x * blockDim.x + threadIdx.x;
    int wvid = gtid >> 6;
    int lane = threadIdx.x & 63;
    if (wvid >= NWAVES) return;
    scatter_wave(frustum, minv, wt, ft, dxp, bxp, acc, wvid, lane);
}

__global__ void k_out(const float* __restrict__ acc, float* __restrict__ out) {
    __shared__ float tile[64][65];
    int vt = blockIdx.y * (NX_ * NY_ / 64) + blockIdx.x;
    out_tile(acc, out, tile, vt, threadIdx.x);
}

// ---------------------------------------------------------------------------
extern "C" void kernel_launch(void* const* d_in, const int* in_sizes, int n_in,
                              void* d_out, int out_size, void* d_ws, size_t ws_size,
                              hipStream_t stream) {
    const float* feats = (const float*)d_in[0];
    const float* depth = (const float*)d_in[1];
    const float* l2i   = (const float*)d_in[2];
    const float* frust = (const float*)d_in[3];
    const float* dx    = (const float*)d_in[4];
    const float* bx    = (const float*)d_in[5];
    float* out = (float*)d_out;

    char* ws = (char*)d_ws;
    float* minv = (float*)ws;
    float* wt  = (float*)(ws + 2048);
    float* ft  = (float*)(ws + 2048 + 4838400);
    float* acc = (float*)(ws + 2048 + 4838400 + 5160960);
    float4* acc4 = (float4*)acc;

    // Pure host-side queries (capture-safe, deterministic)
    int dev = 0;
    hipGetDevice(&dev);
    int coop = 0;
    hipDeviceGetAttribute(&coop, hipDeviceAttributeCooperativeLaunch, dev);
    int perCU = 0;
    hipOccupancyMaxActiveBlocksPerMultiprocessor(&perCU, k_fused, 256, 0);
    int nCU = 0;
    hipDeviceGetAttribute(&nCU, hipDeviceAttributeMultiprocessorCount, dev);
    long maxB = (long)perCU * (long)nCU;
    int nb = (int)(maxB < 1024 ? maxB : 1024);

    if (coop && nb >= NROLE + 64) {
        void* args[] = { (void*)&l2i, (void*)&minv, (void*)&acc4,
                         (void*)&depth, (void*)&wt,
                         (void*)&feats, (void*)&ft,
                         (void*)&frust, (void*)&dx, (void*)&bx,
                         (void*)&acc, (void*)&out };
        hipLaunchCooperativeKernel((const void*)k_fused, dim3(nb), dim3(256),
                                   args, 0, stream);
    } else {
        k_pre<<<1024 + NSMBLK + NTRB, 256, 0, stream>>>(l2i, minv, acc4, depth, wt, feats, ft);
        k_scatter4<<<(NWAVES * 64 + 255) / 256, 256, 0, stream>>>(frust, minv, wt, ft, dx, bx, acc);
        k_out<<<dim3(NX_ * NY_ / 64, B_), 256, 0, stream>>>(acc, out);
    }
}